// Round 1
// baseline (66.566 us; speedup 1.0000x reference)
//
#include <hip/hip_runtime.h>
#include <hip/hip_bf16.h>
#include <math.h>

#define SOM_M 256
#define SOM_N 256
#define SOM_DIM 512
#define NROWS (SOM_M * SOM_N)
#define EPOCHS 100.0f
#define ALPHA 0.3f
#define RADIUS 128.0f

#define DIST_BLOCKS 1024   // 4 waves/block -> 4096 waves, 16 rows per wave

// Pass 1: per-row squared L2 distance + per-block argmin partial.
// One wave (64 lanes) per row: lane reads float4[lane] and float4[lane+64].
__global__ __launch_bounds__(256) void som_dist(
    const float* __restrict__ x, const float* __restrict__ w,
    float* __restrict__ pval, int* __restrict__ pidx) {
    __shared__ float xs[SOM_DIM];
    for (int j = threadIdx.x; j < SOM_DIM; j += 256) xs[j] = x[j];
    __syncthreads();

    const int wave = threadIdx.x >> 6;
    const int lane = threadIdx.x & 63;
    const int gwave = blockIdx.x * 4 + wave;           // 0..4095
    const float4* xs4 = (const float4*)xs;
    const float4 xa = xs4[lane];
    const float4 xb = xs4[lane + 64];

    float best = INFINITY;
    int bidx = 0x7fffffff;

    for (int row = gwave; row < NROWS; row += DIST_BLOCKS * 4) {
        const float4* wr = (const float4*)(w + (size_t)row * SOM_DIM);
        float4 a = wr[lane];
        float4 b = wr[lane + 64];
        float t, d = 0.0f;
        t = a.x - xa.x; d += t * t;
        t = a.y - xa.y; d += t * t;
        t = a.z - xa.z; d += t * t;
        t = a.w - xa.w; d += t * t;
        t = b.x - xb.x; d += t * t;
        t = b.y - xb.y; d += t * t;
        t = b.z - xb.z; d += t * t;
        t = b.w - xb.w; d += t * t;
        // butterfly reduce across the 64-lane wave
        #pragma unroll
        for (int s = 1; s < 64; s <<= 1) d += __shfl_xor(d, s);
        if (d < best) { best = d; bidx = row; }   // strict < keeps first (lowest row)
    }

    __shared__ float bv[4];
    __shared__ int   bi[4];
    if (lane == 0) { bv[wave] = best; bi[wave] = bidx; }
    __syncthreads();
    if (threadIdx.x == 0) {
        float v = bv[0]; int i = bi[0];
        #pragma unroll
        for (int k = 1; k < 4; ++k) {
            if (bv[k] < v || (bv[k] == v && bi[k] < i)) { v = bv[k]; i = bi[k]; }
        }
        pval[blockIdx.x] = v;
        pidx[blockIdx.x] = i;
    }
}

// Pass 2: reduce DIST_BLOCKS partials to the BMU index (first-min tie-break).
__global__ __launch_bounds__(256) void som_argmin(
    const float* __restrict__ pval, const int* __restrict__ pidx,
    int* __restrict__ bmu_out) {
    __shared__ float sv[256];
    __shared__ int   si[256];
    float v = INFINITY; int idx = 0x7fffffff;
    for (int k = threadIdx.x; k < DIST_BLOCKS; k += 256) {
        float pv = pval[k]; int pi = pidx[k];
        if (pv < v || (pv == v && pi < idx)) { v = pv; idx = pi; }
    }
    sv[threadIdx.x] = v; si[threadIdx.x] = idx;
    __syncthreads();
    for (int s = 128; s > 0; s >>= 1) {
        if (threadIdx.x < s) {
            float ov = sv[threadIdx.x + s]; int oi = si[threadIdx.x + s];
            if (ov < sv[threadIdx.x] || (ov == sv[threadIdx.x] && oi < si[threadIdx.x])) {
                sv[threadIdx.x] = ov; si[threadIdx.x] = oi;
            }
        }
        __syncthreads();
    }
    if (threadIdx.x == 0) *bmu_out = si[0];
}

// Pass 3: out = w + lr*(x - w), lr = alpha_op * exp(-grid_d2 / (2*radius_op^2)).
// One float4 per thread. 128 float4 per row.
__global__ __launch_bounds__(256) void som_update(
    const float* __restrict__ x, const float* __restrict__ w,
    const int* __restrict__ it_ptr, const int* __restrict__ bmu_ptr,
    float* __restrict__ out) {
    const int bmu = *bmu_ptr;
    const float lr_decay = 1.0f - (float)(*it_ptr) / EPOCHS;
    const float alpha_op = ALPHA * lr_decay;
    const float radius_op = RADIUS * lr_decay;
    const float inv2r2 = 1.0f / (2.0f * radius_op * radius_op);

    const size_t tid = (size_t)blockIdx.x * 256 + threadIdx.x; // float4 index
    const int row = (int)(tid >> 7);
    const int c4  = (int)(tid & 127);
    const int r = row >> 8, c = row & 255;
    const int br = bmu >> 8, bc = bmu & 255;
    const float dr = (float)(br - r), dc = (float)(bc - c);
    const float lr = alpha_op * expf(-(dr * dr + dc * dc) * inv2r2);

    const float4 wv = ((const float4*)w)[tid];
    const float4 xv = ((const float4*)x)[c4];
    float4 o;
    o.x = wv.x + lr * (xv.x - wv.x);
    o.y = wv.y + lr * (xv.y - wv.y);
    o.z = wv.z + lr * (xv.z - wv.z);
    o.w = wv.w + lr * (xv.w - wv.w);
    ((float4*)out)[tid] = o;
}

extern "C" void kernel_launch(void* const* d_in, const int* in_sizes, int n_in,
                              void* d_out, int out_size, void* d_ws, size_t ws_size,
                              hipStream_t stream) {
    const float* x = (const float*)d_in[0];
    const float* w = (const float*)d_in[1];
    const int* it  = (const int*)d_in[2];
    float* out = (float*)d_out;

    // workspace layout: [0, NB) float pval | [NB, 2NB) int pidx | [2NB] int bmu
    float* pval = (float*)d_ws;
    int*   pidx = (int*)((char*)d_ws + DIST_BLOCKS * sizeof(float));
    int*   bmu  = (int*)((char*)d_ws + 2 * DIST_BLOCKS * sizeof(float));

    som_dist<<<DIST_BLOCKS, 256, 0, stream>>>(x, w, pval, pidx);
    som_argmin<<<1, 256, 0, stream>>>(pval, pidx, bmu);

    const int total_f4 = NROWS * (SOM_DIM / 4);     // 8388608
    som_update<<<total_f4 / 256, 256, 0, stream>>>(x, w, it, bmu, out);
}